// Round 4
// baseline (1455.051 us; speedup 1.0000x reference)
//
#include <hip/hip_runtime.h>

typedef __bf16 bf16x8 __attribute__((ext_vector_type(8)));
typedef float f32x4 __attribute__((ext_vector_type(4)));
typedef unsigned short ushort8 __attribute__((ext_vector_type(8)));

__device__ __forceinline__ unsigned short f2bf(float f) {
  unsigned int u = __builtin_bit_cast(unsigned int, f);
  u += 0x7FFFu + ((u >> 16) & 1u);   // RNE
  return (unsigned short)(u >> 16);
}

// COEF[a][du][u] = weight of W-tap u on x-offset du for output phase a
// (interior-exact; borders p==0 / q==0 recomputed by fix_border).
__constant__ float COEF[2][3][3] = {
    {{0.25f, 0.00f, 0.00f},
     {0.75f, 0.75f, 0.25f},
     {0.00f, 0.25f, 0.75f}},
    {{0.75f, 0.25f, 0.00f},
     {0.25f, 0.75f, 0.75f},
     {0.00f, 0.00f, 0.25f}}
};

// Pack phase-blended weights into MFMA B-fragment layout, bf16.
// pw[ph][kt][nt][lane][8]: lane l holds B[k=kt*32+(l>>4)*8+j][oc=nt*16+(l&15)].
__global__ void pack_weights(const float* __restrict__ w, unsigned short* __restrict__ pw) {
  const int kt = blockIdx.x >> 3, nt = blockIdx.x & 7;
  const int l = threadIdx.x;
  const int tap = kt >> 2, cblk = kt & 3;
  const int du = tap / 3, dv = tap - du * 3;
  const int c0 = cblk * 32 + ((l >> 4) << 3);
  const int oc = nt * 16 + (l & 15);
  float accp[4][8];
#pragma unroll
  for (int ph = 0; ph < 4; ++ph)
#pragma unroll
    for (int j = 0; j < 8; ++j) accp[ph][j] = 0.0f;
#pragma unroll
  for (int u = 0; u < 3; ++u)
#pragma unroll
    for (int v = 0; v < 3; ++v) {
      const float ra0 = COEF[0][du][u], ra1 = COEF[1][du][u];
      const float cb0 = COEF[0][dv][v], cb1 = COEF[1][dv][v];
      const float c00 = ra0 * cb0, c01 = ra0 * cb1, c10 = ra1 * cb0, c11 = ra1 * cb1;
#pragma unroll
      for (int j = 0; j < 8; ++j) {
        const float wv = w[((u * 3 + v) * 128 + c0 + j) * 128 + oc];
        accp[0][j] += c00 * wv;
        accp[1][j] += c01 * wv;
        accp[2][j] += c10 * wv;
        accp[3][j] += c11 * wv;
      }
    }
#pragma unroll
  for (int ph = 0; ph < 4; ++ph) {
    ushort8 o;
#pragma unroll
    for (int j = 0; j < 8; ++j) o[j] = f2bf(accp[ph][j]);
    *(ushort8*)(pw + ((((ph * 36 + kt) * 8 + nt) * 64 + l) << 3)) = o;
  }
}

// Main fused kernel. Block = out tile 16 rows x 32 cols x 128 oc, 256 threads
// (4 waves = 4 phases). Wave tile 128 pos x 128 oc; acc 8x8 f32x4.
// x-tile 11x19x128 bf16 in LDS (53.5 KB -> 2 blocks/CU). A from LDS (8 reads/kt
// serving 64 MFMA), B from L2 (8 loads/kt, 1-deep double buffer). Zero barriers
// in K-loop. M-tile = 16 consecutive out-cols of one row (same-row lane groups).
__global__ __launch_bounds__(256, 2) void fused_direct(
    const float* __restrict__ x, const unsigned short* __restrict__ pw,
    const float* __restrict__ bias, float* __restrict__ out) {
  __shared__ __align__(16) char xlds[11 * 19 * 256];  // 53,504 B

  const int o = blockIdx.x;
  const int blk = (o & 7) * 128 + (o >> 3);  // bijective XCD swizzle (1024 % 8 == 0)
  const int bimg = blk >> 7;
  const int it = (blk >> 3) & 15;  // 16 row-tiles of 16 out rows
  const int jt = blk & 7;          // 8 col-tiles of 32 out cols
  const int I0 = it * 8, J0 = jt * 16;  // x-space origin
  const int tid = threadIdx.x;
  const float* xb = x + bimg * (128 * 128 * 128);

  // ---- Stage x tile: rows I0-1..I0+9, cols J0-1..J0+17 ----
  for (int idx = tid; idx < 11 * 19 * 16; idx += 256) {
    const int cp = idx & 15;
    const int pos = idx >> 4;
    const int xr = pos / 19;
    const int xc = pos - xr * 19;
    const int gi = I0 - 1 + xr;
    const int gj = J0 - 1 + xc;
    ushort8 u8 = {};
    if (((unsigned)gi < 128u) && ((unsigned)gj < 128u)) {
      const float* p = xb + ((gi << 7) + gj) * 128 + (cp << 3);
      const float4 A = *(const float4*)p;
      const float4 Bv = *(const float4*)(p + 4);
      u8[0] = f2bf(A.x); u8[1] = f2bf(A.y); u8[2] = f2bf(A.z); u8[3] = f2bf(A.w);
      u8[4] = f2bf(Bv.x); u8[5] = f2bf(Bv.y); u8[6] = f2bf(Bv.z); u8[7] = f2bf(Bv.w);
    }
    int byte = (pos << 8) + (cp << 4);
    byte ^= (pos & 7) << 4;  // bank swizzle (write side)
    *(ushort8*)(xlds + byte) = u8;
  }
  __syncthreads();

  const int lane = tid & 63;
  const int l15 = lane & 15;
  const int lh = lane >> 4;      // 0..3
  const int wid = tid >> 6;      // wave = phase
  const int a = wid >> 1, b = wid & 1;

  f32x4 acc[8][8] = {};

  const char* pwb = (const char*)pw + wid * 294912 + lane * 16;
  const int colpart = l15 + b;   // x-col contribution independent of kt

#define LOADB(buf, ktv)                                               \
  do {                                                                \
    _Pragma("unroll") for (int n = 0; n < 8; ++n)                     \
        buf[n] = *(const bf16x8*)(pwb + (ktv) * 8192 + n * 1024);     \
  } while (0)

#define BODY(ktv, buf)                                                          \
  do {                                                                          \
    const int tap_ = (ktv) >> 2, cblk_ = (ktv) & 3;                             \
    const int du_ = tap_ / 3, dv_ = tap_ - du_ * 3;                             \
    const int base_ = (a + du_) * 19 + colpart + dv_;                           \
    const int kbyte_ = (cblk_ * 4 + lh) << 4;                                   \
    _Pragma("unroll") for (int h = 0; h < 2; ++h) {                             \
      bf16x8 af[4];                                                             \
      _Pragma("unroll") for (int a2 = 0; a2 < 4; ++a2) {                        \
        const int posa = base_ + (h * 4 + a2) * 19;                             \
        int byte_ = (posa << 8) + kbyte_;                                       \
        byte_ ^= (posa & 7) << 4;  /* same swizzle (read side) */               \
        af[a2] = *(const bf16x8*)(xlds + byte_);                                \
      }                                                                         \
      __builtin_amdgcn_s_setprio(1);                                            \
      _Pragma("unroll") for (int a2 = 0; a2 < 4; ++a2)                          \
          _Pragma("unroll") for (int n = 0; n < 8; ++n)                         \
              acc[h * 4 + a2][n] = __builtin_amdgcn_mfma_f32_16x16x32_bf16(     \
                  af[a2], buf[n], acc[h * 4 + a2][n], 0, 0, 0);                 \
      __builtin_amdgcn_s_setprio(0);                                            \
    }                                                                           \
  } while (0)

  bf16x8 bA[8], bB[8];
  LOADB(bA, 0);
#pragma unroll 1
  for (int kt = 0; kt < 34; kt += 2) {
    LOADB(bB, kt + 1);
    BODY(kt, bA);
    LOADB(bA, kt + 2);
    BODY(kt + 1, bB);
  }
  LOADB(bB, 35);
  BODY(34, bA);
  BODY(35, bB);

#undef LOADB
#undef BODY

  // ---- Epilogue: C/D col=lane&15 (oc within nt), row m=lh*4+reg (out-col j) ----
  float bv[8];
#pragma unroll
  for (int n = 0; n < 8; ++n) bv[n] = bias[n * 16 + l15];
  float* ob = out + bimg * (256 * 256 * 128) + l15;
#pragma unroll
  for (int a_ = 0; a_ < 8; ++a_) {
    const int p = it * 16 + 2 * a_ + a;
#pragma unroll
    for (int jr = 0; jr < 4; ++jr) {
      const int q = jt * 32 + 2 * (lh * 4 + jr) + b;
      float* orow = ob + (p * 256 + q) * 128;
#pragma unroll
      for (int n = 0; n < 8; ++n) orow[n * 16] = acc[a_][n][jr] + bv[n];
    }
  }
}

// Exact recompute of border outputs: row p==0 (all q) and col q==0 (p>=1).
__global__ __launch_bounds__(256) void fix_border(
    const float* __restrict__ x, const float* __restrict__ w,
    const float* __restrict__ bias, float* __restrict__ out) {
  __shared__ float yw[2 * 128 * 34];  // [f][c][ws]

  const int blk = blockIdx.x;
  const int ocg = blk & 7;
  const int chunk = (blk >> 3) & 7;
  const int type = (blk >> 6) & 1;  // 0: row border p=0; 1: col border q=0
  const int bi = blk >> 7;
  const int base0 = chunk * 32;
  const int tid = threadIdx.x;
  const float* xb = x + bi * (128 * 128 * 128);

  for (int idx = tid; idx < 2 * 128 * 34; idx += 256) {
    const int ws = idx % 34;
    const int cf = idx / 34;
    const int c = cf & 127;
    const int f = cf >> 7;
    const int t = base0 - 1 + ws;
    float val = 0.0f;
    if (t >= 0 && t < 256) {
      const int t0 = t >> 1;
      const float hA0 = (t & 1) ? 0.25f : 0.75f;
      const float hA1 = 1.0f - hA0;
      const float hF0 = f ? 0.25f : 0.75f;
      const float hF1 = 1.0f - hF0;
      if (type == 0) {
        const bool ok1 = (t0 + 1) < 128;
        const float v00 = xb[(t0) * 128 + c];
        const float v01 = ok1 ? xb[(t0 + 1) * 128 + c] : 0.0f;
        const float v10 = xb[(128 + t0) * 128 + c];
        const float v11 = ok1 ? xb[(128 + t0 + 1) * 128 + c] : 0.0f;
        val = hF0 * (hA0 * v00 + hA1 * v01) + hF1 * (hA0 * v10 + hA1 * v11);
      } else {
        const bool okr1 = (t0 + 1) < 128;
        const float v00 = xb[(t0 * 128) * 128 + c];
        const float v01 = xb[(t0 * 128 + 1) * 128 + c];
        const float v10 = okr1 ? xb[((t0 + 1) * 128) * 128 + c] : 0.0f;
        const float v11 = okr1 ? xb[((t0 + 1) * 128 + 1) * 128 + c] : 0.0f;
        val = hA0 * (hF0 * v00 + hF1 * v01) + hA1 * (hF0 * v10 + hF1 * v11);
      }
    }
    yw[(f * 128 + c) * 34 + ws] = val;
  }
  __syncthreads();

  const int lane = tid & 63;
  const int wv = tid >> 6;
  const int ch = lane >> 5;
  const int ql = lane & 31;
  const int oc0 = ocg * 16 + wv * 4;

  float acc[4] = {0.f, 0.f, 0.f, 0.f};
#pragma unroll 2
  for (int c0 = 0; c0 < 64; ++c0) {
    const int c = ch * 64 + c0;
#pragma unroll
    for (int tf = 0; tf < 2; ++tf) {
#pragma unroll
      for (int tb = 0; tb < 3; ++tb) {
        const float yv = yw[(tf * 128 + c) * 34 + (ql + tb)];
        const int uu = (type == 0) ? (tf + 1) : tb;
        const int vv = (type == 0) ? tb : (tf + 1);
        const float4 w4 = *(const float4*)(w + ((uu * 3 + vv) * 128 + c) * 128 + oc0);
        acc[0] += yv * w4.x;
        acc[1] += yv * w4.y;
        acc[2] += yv * w4.z;
        acc[3] += yv * w4.w;
      }
    }
  }
#pragma unroll
  for (int j = 0; j < 4; ++j) acc[j] += __shfl_xor(acc[j], 32, 64);

  const int pos = base0 + ql;
  if (ch == 0 && !(type == 1 && pos == 0)) {
    const int p = (type == 0) ? 0 : pos;
    const int q = (type == 0) ? pos : 0;
    const float4 b4 = *(const float4*)(bias + oc0);
    float4 r;
    r.x = acc[0] + b4.x; r.y = acc[1] + b4.y;
    r.z = acc[2] + b4.z; r.w = acc[3] + b4.w;
    *(float4*)(out + bi * (256 * 256 * 128) + (p * 256 + q) * 128 + oc0) = r;
  }
}

extern "C" void kernel_launch(void* const* d_in, const int* in_sizes, int n_in,
                              void* d_out, int out_size, void* d_ws, size_t ws_size,
                              hipStream_t stream) {
  const float* x = (const float*)d_in[0];
  const float* w = (const float*)d_in[1];
  const float* bias = (const float*)d_in[2];
  float* out = (float*)d_out;
  unsigned short* pw = (unsigned short*)d_ws;  // 1,179,648 B used

  pack_weights<<<dim3(288), dim3(64), 0, stream>>>(w, pw);
  fused_direct<<<dim3(1024), dim3(256), 0, stream>>>(x, pw, bias, out);
  fix_border<<<dim3(1024), dim3(256), 0, stream>>>(x, w, bias, out);
}

// Round 5
// 264.430 us; speedup vs baseline: 5.5026x; 5.5026x over previous
//
#include <hip/hip_runtime.h>

typedef __bf16 bf16x8 __attribute__((ext_vector_type(8)));
typedef float f32x4 __attribute__((ext_vector_type(4)));
typedef unsigned short ushort8 __attribute__((ext_vector_type(8)));

__device__ __forceinline__ unsigned short f2bf(float f) {
  unsigned int u = __builtin_bit_cast(unsigned int, f);
  u += 0x7FFFu + ((u >> 16) & 1u);   // RNE
  return (unsigned short)(u >> 16);
}

// COEF[a][du][u] = weight of W-tap u on x-offset du for output phase a
// (interior-exact; borders p==0 / q==0 recomputed by fix_border).
__constant__ float COEF[2][3][3] = {
    {{0.25f, 0.00f, 0.00f},
     {0.75f, 0.75f, 0.25f},
     {0.00f, 0.25f, 0.75f}},
    {{0.75f, 0.25f, 0.00f},
     {0.25f, 0.75f, 0.75f},
     {0.00f, 0.00f, 0.25f}}
};

// Pack phase-blended weights into MFMA B-fragment layout, bf16.
// pw[ph][kt][nt][lane][8]: lane l holds B[k=kt*32+(l>>4)*8+j][oc=nt*16+(l&15)].
__global__ void pack_weights(const float* __restrict__ w, unsigned short* __restrict__ pw) {
  const int kt = blockIdx.x >> 3, nt = blockIdx.x & 7;
  const int l = threadIdx.x;
  const int tap = kt >> 2, cblk = kt & 3;
  const int du = tap / 3, dv = tap - du * 3;
  const int c0 = cblk * 32 + ((l >> 4) << 3);
  const int oc = nt * 16 + (l & 15);
  float accp[4][8];
#pragma unroll
  for (int ph = 0; ph < 4; ++ph)
#pragma unroll
    for (int j = 0; j < 8; ++j) accp[ph][j] = 0.0f;
#pragma unroll
  for (int u = 0; u < 3; ++u)
#pragma unroll
    for (int v = 0; v < 3; ++v) {
      const float ra0 = COEF[0][du][u], ra1 = COEF[1][du][u];
      const float cb0 = COEF[0][dv][v], cb1 = COEF[1][dv][v];
      const float c00 = ra0 * cb0, c01 = ra0 * cb1, c10 = ra1 * cb0, c11 = ra1 * cb1;
#pragma unroll
      for (int j = 0; j < 8; ++j) {
        const float wv = w[((u * 3 + v) * 128 + c0 + j) * 128 + oc];
        accp[0][j] += c00 * wv;
        accp[1][j] += c01 * wv;
        accp[2][j] += c10 * wv;
        accp[3][j] += c11 * wv;
      }
    }
#pragma unroll
  for (int ph = 0; ph < 4; ++ph) {
    ushort8 o;
#pragma unroll
    for (int j = 0; j < 8; ++j) o[j] = f2bf(accp[ph][j]);
    *(ushort8*)(pw + ((((ph * 36 + kt) * 8 + nt) * 64 + l) << 3)) = o;
  }
}

// Main fused kernel. Block = out tile 16 rows x 32 cols x 128 oc, 512 threads.
// 8 waves = (row-phase a, col-phase b, oc-half). Wave tile 128 pos x 64 oc,
// acc[8][4] (128 regs, fits at 2 waves/SIMD — R4's 8x8 spilled to scratch).
// M-tile = one x-row; 16-lane group reads 16 CONSECUTIVE x-cols (4-cyc
// conflict pattern, vs R3's two-row mapping at 8 cyc). A from LDS
// (8 b128/kt serving 32 MFMAs), B from L2 (4 loads/kt, 1-deep dbuf).
// Zero barriers in the K-loop.
__global__ __launch_bounds__(512, 2) void fused_direct(
    const float* __restrict__ x, const unsigned short* __restrict__ pw,
    const float* __restrict__ bias, float* __restrict__ out) {
  __shared__ __align__(16) char xlds[11 * 19 * 256];  // 53,504 B

  const int o = blockIdx.x;
  const int blk = (o & 7) * 128 + (o >> 3);  // bijective XCD swizzle (1024 % 8 == 0)
  const int bimg = blk >> 7;
  const int it = (blk >> 3) & 15;  // 16 row-tiles of 16 out rows
  const int jt = blk & 7;          // 8 col-tiles of 32 out cols
  const int I0 = it * 8, J0 = jt * 16;  // x-space origin
  const int tid = threadIdx.x;
  const float* xb = x + bimg * (128 * 128 * 128);

  // ---- Stage x tile: rows I0-1..I0+9, cols J0-1..J0+17 ----
  for (int idx = tid; idx < 11 * 19 * 16; idx += 512) {
    const int cp = idx & 15;
    const int pos = idx >> 4;
    const int xr = pos / 19;
    const int xc = pos - xr * 19;
    const int gi = I0 - 1 + xr;
    const int gj = J0 - 1 + xc;
    ushort8 u8 = {};
    if (((unsigned)gi < 128u) && ((unsigned)gj < 128u)) {
      const float* p = xb + ((gi << 7) + gj) * 128 + (cp << 3);
      const float4 A = *(const float4*)p;
      const float4 Bv = *(const float4*)(p + 4);
      u8[0] = f2bf(A.x); u8[1] = f2bf(A.y); u8[2] = f2bf(A.z); u8[3] = f2bf(A.w);
      u8[4] = f2bf(Bv.x); u8[5] = f2bf(Bv.y); u8[6] = f2bf(Bv.z); u8[7] = f2bf(Bv.w);
    }
    int byte = (pos << 8) + (cp << 4);
    byte ^= (pos & 7) << 4;  // bank swizzle (write side)
    *(ushort8*)(xlds + byte) = u8;
  }
  __syncthreads();

  const int lane = tid & 63;
  const int l15 = lane & 15;
  const int lh = lane >> 4;        // 0..3
  const int wid = tid >> 6;        // 8 waves
  const int a = (wid >> 2) & 1;    // row phase
  const int b = (wid >> 1) & 1;    // col phase
  const int nhalf = wid & 1;       // oc half
  const int ph = a * 2 + b;

  f32x4 acc[8][4] = {};

  const char* pwb = (const char*)pw + ph * 294912 + nhalf * 4096 + lane * 16;
  const int colpart = l15 + b;  // x-col contribution independent of kt

#define LOADB(buf, ktv)                                               \
  do {                                                                \
    _Pragma("unroll") for (int n = 0; n < 4; ++n)                     \
        buf[n] = *(const bf16x8*)(pwb + (ktv) * 8192 + n * 1024);     \
  } while (0)

#define BODY(ktv, buf)                                                          \
  do {                                                                          \
    const int tap_ = (ktv) >> 2, cblk_ = (ktv) & 3;                             \
    const int du_ = tap_ / 3, dv_ = tap_ - du_ * 3;                             \
    const int base_ = (a + du_) * 19 + colpart + dv_;                           \
    const int kbyte_ = (cblk_ * 4 + lh) << 4;                                   \
    bf16x8 af[8];                                                               \
    _Pragma("unroll") for (int a_ = 0; a_ < 8; ++a_) {                          \
      const int posa = base_ + a_ * 19;                                         \
      int byte_ = (posa << 8) + kbyte_;                                         \
      byte_ ^= (posa & 7) << 4;  /* same swizzle (read side) */                 \
      af[a_] = *(const bf16x8*)(xlds + byte_);                                  \
    }                                                                           \
    __builtin_amdgcn_s_setprio(1);                                              \
    _Pragma("unroll") for (int a_ = 0; a_ < 8; ++a_)                            \
        _Pragma("unroll") for (int n = 0; n < 4; ++n)                           \
            acc[a_][n] = __builtin_amdgcn_mfma_f32_16x16x32_bf16(               \
                af[a_], buf[n], acc[a_][n], 0, 0, 0);                           \
    __builtin_amdgcn_s_setprio(0);                                              \
  } while (0)

  bf16x8 bA[4], bB[4];
  LOADB(bA, 0);
#pragma unroll 1
  for (int kt = 0; kt < 34; kt += 2) {
    LOADB(bB, kt + 1);
    BODY(kt, bA);
    LOADB(bA, kt + 2);
    BODY(kt + 1, bB);
  }
  LOADB(bB, 35);
  BODY(34, bA);
  BODY(35, bB);

#undef LOADB
#undef BODY

  // ---- Epilogue: C/D col=lane&15 (oc), row m=lh*4+reg (out-col index) ----
  float bv[4];
#pragma unroll
  for (int n = 0; n < 4; ++n) bv[n] = bias[nhalf * 64 + n * 16 + l15];
  float* ob = out + bimg * (256 * 256 * 128) + nhalf * 64 + l15;
#pragma unroll
  for (int a_ = 0; a_ < 8; ++a_) {
    const int p = it * 16 + 2 * a_ + a;
#pragma unroll
    for (int jr = 0; jr < 4; ++jr) {
      const int q = jt * 32 + 2 * (lh * 4 + jr) + b;
      float* orow = ob + (p * 256 + q) * 128;
#pragma unroll
      for (int n = 0; n < 4; ++n) orow[n * 16] = acc[a_][n][jr] + bv[n];
    }
  }
}

// Exact recompute of border outputs: row p==0 (all q) and col q==0 (p>=1).
__global__ __launch_bounds__(256) void fix_border(
    const float* __restrict__ x, const float* __restrict__ w,
    const float* __restrict__ bias, float* __restrict__ out) {
  __shared__ float yw[2 * 128 * 34];  // [f][c][ws]

  const int blk = blockIdx.x;
  const int ocg = blk & 7;
  const int chunk = (blk >> 3) & 7;
  const int type = (blk >> 6) & 1;  // 0: row border p=0; 1: col border q=0
  const int bi = blk >> 7;
  const int base0 = chunk * 32;
  const int tid = threadIdx.x;
  const float* xb = x + bi * (128 * 128 * 128);

  for (int idx = tid; idx < 2 * 128 * 34; idx += 256) {
    const int ws = idx % 34;
    const int cf = idx / 34;
    const int c = cf & 127;
    const int f = cf >> 7;
    const int t = base0 - 1 + ws;
    float val = 0.0f;
    if (t >= 0 && t < 256) {
      const int t0 = t >> 1;
      const float hA0 = (t & 1) ? 0.25f : 0.75f;
      const float hA1 = 1.0f - hA0;
      const float hF0 = f ? 0.25f : 0.75f;
      const float hF1 = 1.0f - hF0;
      if (type == 0) {
        const bool ok1 = (t0 + 1) < 128;
        const float v00 = xb[(t0) * 128 + c];
        const float v01 = ok1 ? xb[(t0 + 1) * 128 + c] : 0.0f;
        const float v10 = xb[(128 + t0) * 128 + c];
        const float v11 = ok1 ? xb[(128 + t0 + 1) * 128 + c] : 0.0f;
        val = hF0 * (hA0 * v00 + hA1 * v01) + hF1 * (hA0 * v10 + hA1 * v11);
      } else {
        const bool okr1 = (t0 + 1) < 128;
        const float v00 = xb[(t0 * 128) * 128 + c];
        const float v01 = xb[(t0 * 128 + 1) * 128 + c];
        const float v10 = okr1 ? xb[((t0 + 1) * 128) * 128 + c] : 0.0f;
        const float v11 = okr1 ? xb[((t0 + 1) * 128 + 1) * 128 + c] : 0.0f;
        val = hA0 * (hF0 * v00 + hF1 * v01) + hA1 * (hF0 * v10 + hF1 * v11);
      }
    }
    yw[(f * 128 + c) * 34 + ws] = val;
  }
  __syncthreads();

  const int lane = tid & 63;
  const int wv = tid >> 6;
  const int ch = lane >> 5;
  const int ql = lane & 31;
  const int oc0 = ocg * 16 + wv * 4;

  float acc[4] = {0.f, 0.f, 0.f, 0.f};
#pragma unroll 2
  for (int c0 = 0; c0 < 64; ++c0) {
    const int c = ch * 64 + c0;
#pragma unroll
    for (int tf = 0; tf < 2; ++tf) {
#pragma unroll
      for (int tb = 0; tb < 3; ++tb) {
        const float yv = yw[(tf * 128 + c) * 34 + (ql + tb)];
        const int uu = (type == 0) ? (tf + 1) : tb;
        const int vv = (type == 0) ? tb : (tf + 1);
        const float4 w4 = *(const float4*)(w + ((uu * 3 + vv) * 128 + c) * 128 + oc0);
        acc[0] += yv * w4.x;
        acc[1] += yv * w4.y;
        acc[2] += yv * w4.z;
        acc[3] += yv * w4.w;
      }
    }
  }
#pragma unroll
  for (int j = 0; j < 4; ++j) acc[j] += __shfl_xor(acc[j], 32, 64);

  const int pos = base0 + ql;
  if (ch == 0 && !(type == 1 && pos == 0)) {
    const int p = (type == 0) ? 0 : pos;
    const int q = (type == 0) ? pos : 0;
    const float4 b4 = *(const float4*)(bias + oc0);
    float4 r;
    r.x = acc[0] + b4.x; r.y = acc[1] + b4.y;
    r.z = acc[2] + b4.z; r.w = acc[3] + b4.w;
    *(float4*)(out + bi * (256 * 256 * 128) + (p * 256 + q) * 128 + oc0) = r;
  }
}

extern "C" void kernel_launch(void* const* d_in, const int* in_sizes, int n_in,
                              void* d_out, int out_size, void* d_ws, size_t ws_size,
                              hipStream_t stream) {
  const float* x = (const float*)d_in[0];
  const float* w = (const float*)d_in[1];
  const float* bias = (const float*)d_in[2];
  float* out = (float*)d_out;
  unsigned short* pw = (unsigned short*)d_ws;  // 1,179,648 B used

  pack_weights<<<dim3(288), dim3(64), 0, stream>>>(w, pw);
  fused_direct<<<dim3(1024), dim3(512), 0, stream>>>(x, pw, bias, out);
  fix_border<<<dim3(1024), dim3(256), 0, stream>>>(x, w, bias, out);
}